// Round 4
// baseline (13442.592 us; speedup 1.0000x reference)
//
#include <hip/hip_runtime.h>

// Jordan RNN collapsed recurrence:
//   z_t = Wx@x_t + bh  (parallel GEMM)
//   h_1 = tanh(z_1); h_t = tanh(z_t + (Wh@Wy) h_{t-1} + Wh@by), t>=2  (sequential, persistent)
//   Y   = H@Wy^T + by  (parallel GEMM)
// Seq kernel R4: wave-autonomous. 256 blocks x 8 waves; wave owns 2 output dims.
// No barriers in the t-loop. Cross-block sync: data-as-flag on H (sentinel-poisoned).
// In-block h broadcast: wave wv stages its 1KB slice of h(t-1) into LDS (parity
// double-buffered) + LDS flag = t. Dense W couples all waves step-to-step, which
// bounds drift < 2 steps -> parity buffering is race-free without barriers.
// Weights packed bf16 in VGPRs, consumed by v_dot2_f32_bf16 (2 MAC/instr).
// ws layout (~117.6 MB): same as R3.

#define T_STEPS 2048
#define HID 4096
#define NIN 2048
#define NOUT 2048
#define SENT 0x7F807F80u

typedef unsigned short u16;
typedef unsigned int u32;
typedef __attribute__((ext_vector_type(8))) short bf16x8;
typedef __attribute__((ext_vector_type(4))) float f32x4;

#define DOT2(acc, w_, h_) \
  asm("v_dot2_f32_bf16 %0, %1, %2, %0" : "+v"(acc) : "v"(w_), "v"(h_))

__device__ __forceinline__ u16 f2b(float f) {
  u32 u = __float_as_uint(f);
  u32 r = (u + 0x7fffu + ((u >> 16) & 1u)) >> 16;  // RNE
  return (u16)r;
}
__device__ __forceinline__ float b2f(u16 h) { return __uint_as_float(((u32)h) << 16); }

// ---------------- f32 -> bf16 convert (vectorized; 4 f32 per iter) ----------------
__global__ void conv_kernel(const float* __restrict__ in, u16* __restrict__ out, int n4) {
  int stride = gridDim.x * blockDim.x;
  for (int i = blockIdx.x * blockDim.x + threadIdx.x; i < n4; i += stride) {
    float4 v = *reinterpret_cast<const float4*>(in + (size_t)i * 4);
    uint2 p;
    p.x = (u32)f2b(v.x) | ((u32)f2b(v.y) << 16);
    p.y = (u32)f2b(v.z) | ((u32)f2b(v.w) << 16);
    *reinterpret_cast<uint2*>(out + (size_t)i * 4) = p;
  }
}

// ---------------- pattern fill (H sentinel poison; 16B per iter) ----------------
__global__ void fill_kernel(u32* __restrict__ p, u32 val, int n16) {
  int stride = gridDim.x * blockDim.x;
  uint4 v = {val, val, val, val};
  for (int i = blockIdx.x * blockDim.x + threadIdx.x; i < n16; i += stride)
    reinterpret_cast<uint4*>(p)[i] = v;
}

// ------------- transpose+convert: in [R][C] f32 -> out [C][R] bf16 -------------
__global__ void transpose_conv(const float* __restrict__ in, u16* __restrict__ out, int R, int C) {
  __shared__ float tile[32][33];
  int bx = blockIdx.x * 32;  // along C
  int by = blockIdx.y * 32;  // along R
  int tx = threadIdx.x & 31, ty = threadIdx.x >> 5;
#pragma unroll
  for (int k = 0; k < 32; k += 8)
    tile[ty + k][tx] = in[(size_t)(by + ty + k) * C + bx + tx];
  __syncthreads();
#pragma unroll
  for (int k = 0; k < 32; k += 8)
    out[(size_t)(bx + ty + k) * R + by + tx] = f2b(tile[tx][ty + k]);
}

// ---------------- cvec = Wh @ by (f32, exact) ----------------
__global__ void cvec_kernel(const float* __restrict__ Wh, const float* __restrict__ by,
                            float* __restrict__ c) {
  int k = blockIdx.x, l = threadIdx.x;
  float s = 0.f;
  for (int i = l; i < NOUT; i += 64) s += Wh[(size_t)k * NOUT + i] * by[i];
#pragma unroll
  for (int m = 32; m; m >>= 1) s += __shfl_xor(s, m, 64);
  if (l == 0) c[k] = s;
}

// ---------------- bf16 GEMM: C[M][N] = A[M][K] @ Bt[N][K]^T (+bias[col]) ----------------
__global__ __launch_bounds__(256) void gemm_bt(
    const u16* __restrict__ A, const u16* __restrict__ Bt,
    int M, int N, int K,
    float* __restrict__ Cf, u16* __restrict__ Cb,
    const float* __restrict__ bias) {
  __shared__ __align__(16) u16 As[64][40];
  __shared__ __align__(16) u16 Bs[64][40];
  const int tid = threadIdx.x;
  const int wave = tid >> 6;
  const int lane = tid & 63;
  const int m0 = blockIdx.y * 64;
  const int n0 = blockIdx.x * 64;
  const int lr = tid >> 2;
  const int lc = (tid & 3) << 3;
  const int frow = lane & 15;
  const int koff = (lane >> 4) << 3;

  f32x4 acc0 = {0.f, 0.f, 0.f, 0.f};
  f32x4 acc1 = acc0, acc2 = acc0, acc3 = acc0;

  const u16* pA = A + (size_t)(m0 + lr) * K + lc;
  const u16* pB = Bt + (size_t)(n0 + lr) * K + lc;

  for (int k0 = 0; k0 < K; k0 += 32) {
    uint4 va = *reinterpret_cast<const uint4*>(pA + k0);
    uint4 vb = *reinterpret_cast<const uint4*>(pB + k0);
    *reinterpret_cast<uint4*>(&As[lr][lc]) = va;
    *reinterpret_cast<uint4*>(&Bs[lr][lc]) = vb;
    __syncthreads();
    bf16x8 af = *reinterpret_cast<const bf16x8*>(&As[(wave << 4) + frow][koff]);
    bf16x8 b0 = *reinterpret_cast<const bf16x8*>(&Bs[frow][koff]);
    bf16x8 b1 = *reinterpret_cast<const bf16x8*>(&Bs[16 + frow][koff]);
    bf16x8 b2 = *reinterpret_cast<const bf16x8*>(&Bs[32 + frow][koff]);
    bf16x8 b3 = *reinterpret_cast<const bf16x8*>(&Bs[48 + frow][koff]);
    acc0 = __builtin_amdgcn_mfma_f32_16x16x32_bf16(af, b0, acc0, 0, 0, 0);
    acc1 = __builtin_amdgcn_mfma_f32_16x16x32_bf16(af, b1, acc1, 0, 0, 0);
    acc2 = __builtin_amdgcn_mfma_f32_16x16x32_bf16(af, b2, acc2, 0, 0, 0);
    acc3 = __builtin_amdgcn_mfma_f32_16x16x32_bf16(af, b3, acc3, 0, 0, 0);
    __syncthreads();
  }

  const int crow = m0 + (wave << 4) + ((lane >> 4) << 2);
  const int ccol = n0 + (lane & 15);
  float bv0 = bias ? bias[ccol] : 0.f;
  float bv1 = bias ? bias[ccol + 16] : 0.f;
  float bv2 = bias ? bias[ccol + 32] : 0.f;
  float bv3 = bias ? bias[ccol + 48] : 0.f;
  if (Cf) {
#pragma unroll
    for (int r = 0; r < 4; ++r) {
      size_t base = (size_t)(crow + r) * N + ccol;
      Cf[base] = acc0[r] + bv0;
      Cf[base + 16] = acc1[r] + bv1;
      Cf[base + 32] = acc2[r] + bv2;
      Cf[base + 48] = acc3[r] + bv3;
    }
  } else {
#pragma unroll
    for (int r = 0; r < 4; ++r) {
      size_t base = (size_t)(crow + r) * N + ccol;
      Cb[base] = f2b(acc0[r] + bv0);
      Cb[base + 16] = f2b(acc1[r] + bv1);
      Cb[base + 32] = f2b(acc2[r] + bv2);
      Cb[base + 48] = f2b(acc3[r] + bv3);
    }
  }
}

// ---------------- sequential recurrence R4 (wave-autonomous, no in-loop barriers) ----
// 256 blocks x 512 threads (8 waves). Wave wv of block b owns output dims
// r0=16b+2wv, r0+1 (weights: 2 rows x 4096 bf16 packed = 64 VGPR/lane).
// Per step t>=2, parity p=(t-1)&1:
//   1. spin on own global region of h(t-1): u32 slots [256wv+4lane, +4)
//   2. stage 16B into hbuf[p], release flag[p][wv]=t (lane 0)
//   3. acquire-poll all 8 flags >= t
//   4. 8x ds_read_b128 + 64x v_dot2_f32_bf16 (2 rows x 4096 cols)
//   5. butterfly reduce both rows, tanh (even/odd lane parallel), lane0 stores u32
__global__ __launch_bounds__(512, 2) void seq_kernel(
    const u16* __restrict__ Wm, const u16* __restrict__ Zb,
    const float* __restrict__ cvec, u16* __restrict__ H, int T) {
  const int tid = threadIdx.x;
  const int lane = tid & 63;
  const int wv = tid >> 6;
  const int b = blockIdx.x;
  const int r0 = b * 16 + wv * 2;

  // packed bf16 weights: wp0/wp1[c] = rows r0/r0+1, cols [c*512 + lane*8, +8)
  uint4 wp0[8], wp1[8];
  {
    const u16* wr = Wm + (size_t)r0 * HID + (lane << 3);
#pragma unroll
    for (int c = 0; c < 8; ++c) {
      wp0[c] = *reinterpret_cast<const uint4*>(wr + (c << 9));
      wp1[c] = *reinterpret_cast<const uint4*>(wr + HID + (c << 9));
    }
  }
  const float c0 = cvec[r0];
  const float c1 = cvec[r0 + 1];

  __shared__ __align__(16) u32 hbuf[2][HID / 2];  // 16 KB, parity double-buffered
  __shared__ u32 flags[2][8];
  if (tid < 16) reinterpret_cast<u32*>(flags)[tid] = 0;
  __syncthreads();  // once, before the loop

  const u32* Hu = reinterpret_cast<const u32*>(H);
  u32* Hw = reinterpret_cast<u32*>(H);
  const u32* Zu = reinterpret_cast<const u32*>(Zb);
  const int slot = (b << 3) + wv;  // this wave's u32 slot in h rows

  // ---- t = 1: h = tanh(z) ----
  {
    u32 zq = Zu[slot];
    float pre0 = __uint_as_float(zq << 16);
    float pre1 = __uint_as_float(zq & 0xffff0000u);
    float pre = (lane & 1) ? pre1 : pre0;
    float ax = fabsf(pre);
    float e = __expf(2.f * ax);
    float th = 1.f - 2.f / (e + 1.f);
    th = (pre < 0.f) ? -th : th;
    float tho = __shfl_xor(th, 1, 64);
    if (lane == 0) {
      u32 pk = (u32)f2b(th) | ((u32)f2b(tho) << 16);
      __hip_atomic_store(Hw + slot, pk, __ATOMIC_RELAXED, __HIP_MEMORY_SCOPE_AGENT);
    }
  }

  for (int t = 2; t <= T; ++t) {
    const int p = (t - 1) & 1;
    // z prefetch (issues early; consumed at the end)
    u32 zq = Zu[(size_t)(t - 1) * (HID / 2) + slot];

    // 1. spin on own global region of h(t-1)
    const u32* hsrc = Hu + (size_t)(t - 2) * (HID / 2) + (wv << 8) + (lane << 2);
    u32 q0, q1, q2, q3;
    for (;;) {
      q0 = __hip_atomic_load(hsrc + 0, __ATOMIC_RELAXED, __HIP_MEMORY_SCOPE_AGENT);
      q1 = __hip_atomic_load(hsrc + 1, __ATOMIC_RELAXED, __HIP_MEMORY_SCOPE_AGENT);
      q2 = __hip_atomic_load(hsrc + 2, __ATOMIC_RELAXED, __HIP_MEMORY_SCOPE_AGENT);
      q3 = __hip_atomic_load(hsrc + 3, __ATOMIC_RELAXED, __HIP_MEMORY_SCOPE_AGENT);
      if (q0 != SENT && q1 != SENT && q2 != SENT && q3 != SENT) break;
    }

    // 2. stage into LDS + release flag
    {
      uint4 st = {q0, q1, q2, q3};
      *reinterpret_cast<uint4*>(&hbuf[p][(wv << 8) + (lane << 2)]) = st;
      if (lane == 0)
        __hip_atomic_store(&flags[p][wv], (u32)t, __ATOMIC_RELEASE,
                           __HIP_MEMORY_SCOPE_WORKGROUP);
    }

    // 3. wait for all 8 regions of this parity
    for (;;) {
      bool ok = true;
#pragma unroll
      for (int r = 0; r < 8; ++r)
        ok &= (__hip_atomic_load(&flags[p][r], __ATOMIC_RELAXED,
                                 __HIP_MEMORY_SCOPE_WORKGROUP) >= (u32)t);
      if (ok) break;
    }
    __builtin_amdgcn_fence(__ATOMIC_ACQUIRE, "workgroup");

    // 4. dot product: 2 rows x 4096 cols, this lane's 64 cols per chunk structure
    float a0 = 0.f, a1 = 0.f;
#pragma unroll
    for (int c = 0; c < 8; ++c) {
      uint4 hq = *reinterpret_cast<const uint4*>(&hbuf[p][(c << 8) + (lane << 2)]);
      DOT2(a0, wp0[c].x, hq.x); DOT2(a0, wp0[c].y, hq.y);
      DOT2(a0, wp0[c].z, hq.z); DOT2(a0, wp0[c].w, hq.w);
      DOT2(a1, wp1[c].x, hq.x); DOT2(a1, wp1[c].y, hq.y);
      DOT2(a1, wp1[c].z, hq.z); DOT2(a1, wp1[c].w, hq.w);
    }

    // 5. butterfly reduce both rows across the wave
#pragma unroll
    for (int m = 32; m; m >>= 1) {
      a0 += __shfl_xor(a0, m, 64);
      a1 += __shfl_xor(a1, m, 64);
    }

    float pre0 = a0 + __uint_as_float(zq << 16) + c0;
    float pre1 = a1 + __uint_as_float(zq & 0xffff0000u) + c1;
    float pre = (lane & 1) ? pre1 : pre0;
    float ax = fabsf(pre);
    float e = __expf(2.f * ax);
    float th = 1.f - 2.f / (e + 1.f);  // |pre| large -> e=inf -> th=1 (no NaN)
    th = (pre < 0.f) ? -th : th;
    float tho = __shfl_xor(th, 1, 64);
    if (lane == 0) {
      u32 pk = (u32)f2b(th) | ((u32)f2b(tho) << 16);
      __hip_atomic_store(Hw + (size_t)(t - 1) * (HID / 2) + slot, pk,
                         __ATOMIC_RELAXED, __HIP_MEMORY_SCOPE_AGENT);
    }
  }
}

extern "C" void kernel_launch(void* const* d_in, const int* in_sizes, int n_in,
                              void* d_out, int out_size, void* d_ws, size_t ws_size,
                              hipStream_t stream) {
  (void)in_sizes; (void)n_in; (void)out_size; (void)ws_size;
  const float* x  = (const float*)d_in[0];
  const float* Wx = (const float*)d_in[1];
  const float* Wh = (const float*)d_in[2];
  const float* Wy = (const float*)d_in[3];
  const float* bh = (const float*)d_in[4];
  const float* by = (const float*)d_in[5];
  float* out = (float*)d_out;

  char* ws = (char*)d_ws;
  const size_t MB = 1ull << 20;
  u16* Whb  = (u16*)(ws + 0 * MB);
  u16* WyTb = (u16*)(ws + 16 * MB);
  u16* Wyb  = (u16*)(ws + 32 * MB);
  u16* Zb   = (u16*)(ws + 48 * MB);
  u16* Hb   = (u16*)(ws + 64 * MB);
  u16* xb   = (u16*)(ws + 80 * MB);
  u16* Wxb  = (u16*)(ws + 88 * MB);
  u16* Wmb  = (u16*)(ws + 80 * MB);  // overlaps xb/Wxb; written only after Z GEMM
  float* cv = (float*)(ws + 112 * MB);

  conv_kernel<<<1024, 256, 0, stream>>>(x, xb, (T_STEPS * NIN) / 4);
  conv_kernel<<<1024, 256, 0, stream>>>(Wx, Wxb, (HID * NIN) / 4);
  conv_kernel<<<1024, 256, 0, stream>>>(Wh, Whb, (HID * NOUT) / 4);
  conv_kernel<<<1024, 256, 0, stream>>>(Wy, Wyb, (NOUT * HID) / 4);
  transpose_conv<<<dim3(HID / 32, NOUT / 32), 256, 0, stream>>>(Wy, WyTb, NOUT, HID);
  cvec_kernel<<<HID, 64, 0, stream>>>(Wh, by, cv);
  // poison H with bf16-pair sentinel: T*HID bf16 = T*HID/8 uint4 writes (16B each)
  fill_kernel<<<1024, 256, 0, stream>>>((u32*)Hb, SENT, (T_STEPS * HID) / 8);

  // Z[2048][4096] = x @ Wx^T + bh   (bf16 out)
  gemm_bt<<<dim3(HID / 64, T_STEPS / 64), 256, 0, stream>>>(
      xb, Wxb, T_STEPS, HID, NIN, nullptr, Zb, bh);
  // Wm[4096][4096] = Wh @ Wy        (bf16 out; uses WyT for B^T form)
  gemm_bt<<<dim3(HID / 64, HID / 64), 256, 0, stream>>>(
      Whb, WyTb, HID, HID, NOUT, nullptr, Wmb, nullptr);

  int T = T_STEPS;
  void* args[] = {(void*)&Wmb, (void*)&Zb, (void*)&cv, (void*)&Hb, (void*)&T};
  hipLaunchCooperativeKernel((const void*)seq_kernel, dim3(256), dim3(512), args, 0, stream);

  // Y[2048][2048] = H @ Wy^T + by   (f32 out -> d_out)
  gemm_bt<<<dim3(NOUT / 64, T_STEPS / 64), 256, 0, stream>>>(
      Hb, Wyb, T_STEPS, NOUT, HID, out, nullptr, by);
}